// Round 17
// baseline (65.083 us; speedup 1.0000x reference)
//
#include <hip/hip_runtime.h>

#define S 512
#define Dm 512

typedef __bf16 bf16x8 __attribute__((ext_vector_type(8)));
typedef float f32x4 __attribute__((ext_vector_type(4)));

// ---------------- bf16 MFMA GEMM with inline fp32->bf16 conversion (r8) ----------------
template<bool A_BF16>
__global__ __launch_bounds__(256) void gemm_icvt(
    const void* __restrict__ Aptr,
    const float* __restrict__ W0, const float* __restrict__ W1, const float* __restrict__ W2,
    const float* __restrict__ b0, const float* __restrict__ b1, const float* __restrict__ b2,
    float* __restrict__ O0, float* __restrict__ O1, float* __restrict__ O2)
{
    int blk = blockIdx.x;
    int m = blk >> 8;
    int tile = blk & 255;
    const float* W = (m == 0) ? W0 : (m == 1) ? W1 : W2;
    const float* bias = (m == 0) ? b0 : (m == 1) ? b1 : b2;
    float* O = (m == 0) ? O0 : (m == 1) ? O1 : O2;
    int rt = tile >> 4, ct = tile & 15;

    int u = threadIdx.x;
    int w = u >> 6, lane = u & 63;
    int r = lane & 15, kg = lane >> 4;

    int row0 = (rt << 5) + ((w >> 1) << 4);
    int col0 = (ct << 5) + ((w & 1) << 4);

    const float* Bp = W + (kg << 3) * Dm + col0 + r;

    f32x4 acc = {0.f, 0.f, 0.f, 0.f};

    #pragma unroll 4
    for (int k0 = 0; k0 < Dm; k0 += 32) {
        bf16x8 a;
        if constexpr (A_BF16) {
            const __bf16* Ab = (const __bf16*)Aptr;
            a = *(const bf16x8*)(Ab + (row0 + r) * Dm + k0 + (kg << 3));
        } else {
            const float* Af = (const float*)Aptr;
            float4 a0 = *(const float4*)(Af + (row0 + r) * Dm + k0 + (kg << 3));
            float4 a1 = *(const float4*)(Af + (row0 + r) * Dm + k0 + (kg << 3) + 4);
            a[0] = (__bf16)a0.x; a[1] = (__bf16)a0.y; a[2] = (__bf16)a0.z; a[3] = (__bf16)a0.w;
            a[4] = (__bf16)a1.x; a[5] = (__bf16)a1.y; a[6] = (__bf16)a1.z; a[7] = (__bf16)a1.w;
        }
        bf16x8 b;
        #pragma unroll
        for (int t = 0; t < 8; ++t)
            b[t] = (__bf16)Bp[(k0 + t) * Dm];
        acc = __builtin_amdgcn_mfma_f32_16x16x32_bf16(a, b, acc, 0, 0, 0);
    }

    int orow = row0 + (kg << 2);
    float bb = bias[col0 + r];
    #pragma unroll
    for (int t = 0; t < 4; ++t)
        O[(orow + t) * Dm + col0 + r] = acc[t] + bb;
}

// true opaque zero: stays 0 but compiler can't prove wave-uniformity
__device__ __forceinline__ int opaque_zero() {
    int lz = 0;
    asm volatile("" : "+v"(lz));
    return lz;
}

// ---------------- z-pass: LDS-staged Q + vmcnt-pipelined vector-broadcast K ----------------
// grid 512 = 8 heads * 8 i-tiles(64) * 8 j-tiles(64). 512 thr = 8 waves; wave w: 8 j's.
// K rows ride the VECTOR path (in-order vmcnt) with 2-row double buffering:
// prefetch(j+1) issued before compute(j) -> wait already satisfied when compute starts.
__global__ __launch_bounds__(512) void zfast_kernel(
    const float* __restrict__ Q, const float* __restrict__ K,
    const float* __restrict__ mask, const float* __restrict__ gamma,
    const float* __restrict__ alpha,
    float* __restrict__ zp, float* __restrict__ Zpart)
{
    int blk = blockIdx.x;
    int h  = blk >> 6;
    int it = (blk >> 3) & 7;
    int jt = blk & 7;
    int i0 = it << 6;
    int j0 = jt << 6;
    int c0 = h << 6;

    int u = threadIdx.x;
    int w = u >> 6, lane = u & 63;

    __shared__ char smem_raw[18688];
    float (*Qs)[68]      = (float (*)[68])smem_raw;
    float (*zsT)[65]     = (float (*)[65])smem_raw;
    float (*partial)[64] = (float (*)[64])(smem_raw + 16640);

    // hoist all scalar values BEFORE the loop (no lgkm drains inside)
    float sc = 1.0f / (gamma[0] * 8.0f);
    float al = alpha[0];
    int jb = w << 3;
    float mreg[8];
    #pragma unroll
    for (int jj = 0; jj < 8; ++jj)
        mreg[jj] = (1.0f - mask[j0 + jb + jj]) * 1e6f;

    // ---- stage Q tile coalesced, then per-lane row from LDS ----
    {
        int row = u >> 3;
        int cg = (u & 7) << 3;
        float4 a0 = *(const float4*)(Q + (i0 + row) * Dm + c0 + cg);
        float4 a1 = *(const float4*)(Q + (i0 + row) * Dm + c0 + cg + 4);
        *(float4*)&Qs[row][cg] = a0;
        *(float4*)&Qs[row][cg + 4] = a1;
    }
    __syncthreads();

    float qreg[64];
    #pragma unroll
    for (int t = 0; t < 16; ++t) {
        float4 qv = *(const float4*)&Qs[lane][t << 2];
        qreg[4 * t + 0] = qv.x; qreg[4 * t + 1] = qv.y;
        qreg[4 * t + 2] = qv.z; qreg[4 * t + 3] = qv.w;
    }
    __syncthreads();        // Qs dead; zsT/partial live

    int lz = opaque_zero();
    const float* kbase = K + (j0 + jb) * Dm + c0 + lz;   // per-lane (vector) path, identical addrs

    float zsum = 0.f;
    float4 kb0[16], kb1[16];

    auto prefetch = [&](float4 (&buf)[16], int row) {
        const float* kr = kbase + row * Dm;
        #pragma unroll
        for (int t = 0; t < 16; ++t)
            buf[t] = *(const float4*)(kr + (t << 2));
    };
    auto compute = [&](const float4 (&kv)[16], int jj) {
        float a0 = 0.f, a1 = 0.f, a2 = 0.f, a3 = 0.f;
        #pragma unroll
        for (int t = 0; t < 16; ++t) {
            a0 += fabsf(qreg[4 * t + 0] - kv[t].x);
            a1 += fabsf(qreg[4 * t + 1] - kv[t].y);
            a2 += fabsf(qreg[4 * t + 2] - kv[t].z);
            a3 += fabsf(qreg[4 * t + 3] - kv[t].w);
        }
        float zpv = fmaxf((a0 + a1 + a2 + a3) * sc - al, 0.0f) + mreg[jj];
        zsT[jb + jj][lane] = zpv;
        zsum += zpv;
    };

    prefetch(kb0, 0);
    prefetch(kb1, 1); compute(kb0, 0);
    prefetch(kb0, 2); compute(kb1, 1);
    prefetch(kb1, 3); compute(kb0, 2);
    prefetch(kb0, 4); compute(kb1, 3);
    prefetch(kb1, 5); compute(kb0, 4);
    prefetch(kb0, 6); compute(kb1, 5);
    prefetch(kb1, 7); compute(kb0, 6);
    compute(kb1, 7);

    partial[w][lane] = zsum;
    __syncthreads();

    if (u < 64) {
        float zs8 = 0.f;
        #pragma unroll
        for (int p = 0; p < 8; ++p) zs8 += partial[p][u];
        Zpart[((h << 9) + i0 + u) * 8 + jt] = zs8;
    }

    {
        int il = u >> 3;
        int jg = (u & 7) << 3;
        float* orow = zp + ((h << 9) + i0 + il) * S + j0 + jg;
        #pragma unroll
        for (int q4 = 0; q4 < 2; ++q4) {
            float4 o;
            o.x = zsT[jg + (q4 << 2) + 0][il];
            o.y = zsT[jg + (q4 << 2) + 1][il];
            o.z = zsT[jg + (q4 << 2) + 2][il];
            o.w = zsT[jg + (q4 << 2) + 3][il];
            *(float4*)(orow + (q4 << 2)) = o;
        }
    }
}

// ---------------- ctx (r8, unchanged): sum_j max(v,z') - Zsum ----------------
__global__ __launch_bounds__(512) void ctx_kernel(
    const float* __restrict__ V, const float* __restrict__ zp,
    const float* __restrict__ Zpart, __bf16* __restrict__ ctxb)
{
    int blk = blockIdx.x;
    int h = blk >> 6;
    int it = blk & 63;
    int i0 = it << 3;
    int c0 = h << 6;
    int u = threadIdx.x;
    int w = u >> 6, lane = u & 63;

    __shared__ float part[8][8][64];

    int wu = __builtin_amdgcn_readfirstlane(w);
    float acc[8][4] = {};

    #pragma unroll
    for (int cch = 0; cch < 4; ++cch) {
        int jg = (cch << 7) + (wu << 4);
        float vv[16];
        #pragma unroll
        for (int t = 0; t < 16; ++t)
            vv[t] = V[(jg + t) * Dm + c0 + lane];

        const float* zbase = zp + ((h << 9) + i0) * S + jg;
        #pragma unroll
        for (int ii = 0; ii < 8; ++ii) {
            const float* zrow = zbase + ii * S;
            #pragma unroll
            for (int q4 = 0; q4 < 4; ++q4) {
                float4 z4 = *(const float4*)(zrow + (q4 << 2));
                acc[ii][0] += fmaxf(vv[(q4 << 2) + 0], z4.x);
                acc[ii][1] += fmaxf(vv[(q4 << 2) + 1], z4.y);
                acc[ii][2] += fmaxf(vv[(q4 << 2) + 2], z4.z);
                acc[ii][3] += fmaxf(vv[(q4 << 2) + 3], z4.w);
            }
        }
    }

    #pragma unroll
    for (int ii = 0; ii < 8; ++ii)
        part[w][ii][lane] = (acc[ii][0] + acc[ii][1]) + (acc[ii][2] + acc[ii][3]);
    __syncthreads();
    {
        int ii = u >> 6;
        float s = 0.f;
        #pragma unroll
        for (int ww = 0; ww < 8; ++ww) s += part[ww][ii][lane];
        float zsum = 0.f;
        const float* zpr = Zpart + ((h << 9) + (i0 + ii)) * 8;
        #pragma unroll
        for (int p = 0; p < 8; ++p) zsum += zpr[p];
        ctxb[(i0 + ii) * Dm + c0 + lane] = (__bf16)(s - zsum);
    }
}

extern "C" void kernel_launch(void* const* d_in, const int* in_sizes, int n_in,
                              void* d_out, int out_size, void* d_ws, size_t ws_size,
                              hipStream_t stream) {
    const float* hs    = (const float*)d_in[0];
    const float* mask  = (const float*)d_in[1];
    const float* Wq    = (const float*)d_in[2];
    const float* bq    = (const float*)d_in[3];
    const float* Wk    = (const float*)d_in[4];
    const float* bk    = (const float*)d_in[5];
    const float* Wv    = (const float*)d_in[6];
    const float* bv    = (const float*)d_in[7];
    const float* Wo    = (const float*)d_in[8];
    const float* bo    = (const float*)d_in[9];
    const float* gamma = (const float*)d_in[10];
    const float* alpha = (const float*)d_in[11];
    float* out = (float*)d_out;

    char* base = (char*)d_ws;
    float*  zp    = (float*)(base);                               // 8 MB
    float*  Zpart = (float*)(base + (8u << 20));                  // 128 KB
    float*  Qb    = (float*)(base + (8u << 20) + (128u << 10));   // 1 MB
    float*  Kb    = Qb + S * Dm;                                  // 1 MB
    float*  Vb    = Kb + S * Dm;                                  // 1 MB
    __bf16* Cbf   = (__bf16*)(Vb + S * Dm);                       // 0.5 MB

    hipLaunchKernelGGL((gemm_icvt<false>), dim3(768), dim3(256), 0, stream,
                       (const void*)hs, Wq, Wk, Wv, bq, bk, bv, Qb, Kb, Vb);
    hipLaunchKernelGGL(zfast_kernel, dim3(512), dim3(512), 0, stream,
                       Qb, Kb, mask, gamma, alpha, zp, Zpart);
    hipLaunchKernelGGL(ctx_kernel, dim3(512), dim3(512), 0, stream,
                       Vb, zp, Zpart, Cbf);
    hipLaunchKernelGGL((gemm_icvt<true>), dim3(256), dim3(256), 0, stream,
                       (const void*)Cbf, Wo, Wo, Wo, bo, bo, bo, out, out, out);
}

// Round 18
// 56.827 us; speedup vs baseline: 1.1453x; 1.1453x over previous
//
#include <hip/hip_runtime.h>

#define S 512
#define Dm 512

typedef __bf16 bf16x8 __attribute__((ext_vector_type(8)));
typedef float f32x4 __attribute__((ext_vector_type(4)));

// ---------------- bf16 MFMA GEMM with inline fp32->bf16 conversion ----------------
// TRANSQK: matrices m<2 (Q,K) are written TRANSPOSED (O^T[col][row]) so the
// z-pass can read KT[d][j] coalesced and QT[d][i] as contiguous scalar rows.
template<bool A_BF16, bool TRANSQK>
__global__ __launch_bounds__(256) void gemm_icvt(
    const void* __restrict__ Aptr,
    const float* __restrict__ W0, const float* __restrict__ W1, const float* __restrict__ W2,
    const float* __restrict__ b0, const float* __restrict__ b1, const float* __restrict__ b2,
    float* __restrict__ O0, float* __restrict__ O1, float* __restrict__ O2)
{
    int blk = blockIdx.x;
    int m = blk >> 8;
    int tile = blk & 255;
    const float* W = (m == 0) ? W0 : (m == 1) ? W1 : W2;
    const float* bias = (m == 0) ? b0 : (m == 1) ? b1 : b2;
    float* O = (m == 0) ? O0 : (m == 1) ? O1 : O2;
    int rt = tile >> 4, ct = tile & 15;

    int u = threadIdx.x;
    int w = u >> 6, lane = u & 63;
    int r = lane & 15, kg = lane >> 4;

    int row0 = (rt << 5) + ((w >> 1) << 4);
    int col0 = (ct << 5) + ((w & 1) << 4);

    const float* Bp = W + (kg << 3) * Dm + col0 + r;

    f32x4 acc = {0.f, 0.f, 0.f, 0.f};

    #pragma unroll 4
    for (int k0 = 0; k0 < Dm; k0 += 32) {
        bf16x8 a;
        if constexpr (A_BF16) {
            const __bf16* Ab = (const __bf16*)Aptr;
            a = *(const bf16x8*)(Ab + (row0 + r) * Dm + k0 + (kg << 3));
        } else {
            const float* Af = (const float*)Aptr;
            float4 a0 = *(const float4*)(Af + (row0 + r) * Dm + k0 + (kg << 3));
            float4 a1 = *(const float4*)(Af + (row0 + r) * Dm + k0 + (kg << 3) + 4);
            a[0] = (__bf16)a0.x; a[1] = (__bf16)a0.y; a[2] = (__bf16)a0.z; a[3] = (__bf16)a0.w;
            a[4] = (__bf16)a1.x; a[5] = (__bf16)a1.y; a[6] = (__bf16)a1.z; a[7] = (__bf16)a1.w;
        }
        bf16x8 b;
        #pragma unroll
        for (int t = 0; t < 8; ++t)
            b[t] = (__bf16)Bp[(k0 + t) * Dm];
        acc = __builtin_amdgcn_mfma_f32_16x16x32_bf16(a, b, acc, 0, 0, 0);
    }

    int orow = row0 + (kg << 2);
    float bb = bias[col0 + r];

    if constexpr (TRANSQK) {
        if (m < 2) {
            // transposed write: one contiguous float4 along the row axis
            float4 o = make_float4(acc[0] + bb, acc[1] + bb, acc[2] + bb, acc[3] + bb);
            *(float4*)(O + (col0 + r) * S + orow) = o;
            return;
        }
    }
    #pragma unroll
    for (int t = 0; t < 4; ++t)
        O[(orow + t) * Dm + col0 + r] = acc[t] + bb;
}

// ---------------- z-pass, ctx-shaped: lane = j (coalesced KT), Q rows scalar ----------------
// grid 512 = 8 heads * 64 i-tiles(8 rows). 512 thr = 8 waves; thread j = w*64+lane.
// Per d-step: 1 coalesced dword (KT) + 8 uniform floats (QT) -> 16 VALU. No syncthreads.
__global__ __launch_bounds__(512) void zT_kernel(
    const float* __restrict__ QT, const float* __restrict__ KT,
    const float* __restrict__ mask, const float* __restrict__ gamma,
    const float* __restrict__ alpha,
    float* __restrict__ zp, float* __restrict__ Zpart)
{
    int blk = blockIdx.x;
    int h  = blk >> 6;
    int it = blk & 63;
    int i0 = it << 3;
    int c0 = h << 6;

    int u = threadIdx.x;
    int w = u >> 6, lane = u & 63;
    int jj = (w << 6) + lane;          // this thread's j

    const float* kcol = KT + (c0 * S) + jj;   // stride S per d, coalesced across lanes
    const float* qrow = QT + (c0 * S) + i0;   // block-uniform, 8 contiguous floats per d

    float acc[8] = {};
    #pragma unroll 4
    for (int d = 0; d < 64; ++d) {
        float kv = kcol[d * S];
        float4 qa = *(const float4*)(qrow + d * S);
        float4 qb = *(const float4*)(qrow + d * S + 4);
        acc[0] += fabsf(qa.x - kv);
        acc[1] += fabsf(qa.y - kv);
        acc[2] += fabsf(qa.z - kv);
        acc[3] += fabsf(qa.w - kv);
        acc[4] += fabsf(qb.x - kv);
        acc[5] += fabsf(qb.y - kv);
        acc[6] += fabsf(qb.z - kv);
        acc[7] += fabsf(qb.w - kv);
    }

    float sc = 1.0f / (gamma[0] * 8.0f);
    float al = alpha[0];
    float madd = (1.0f - mask[jj]) * 1e6f;

    float zpv[8];
    #pragma unroll
    for (int r = 0; r < 8; ++r) {
        zpv[r] = fmaxf(acc[r] * sc - al, 0.0f) + madd;
        zp[((h << 9) + i0 + r) * S + jj] = zpv[r];   // coalesced across lanes
    }

    // Zsum per row: butterfly across the wave's 64 j, then Zpart[row*8 + w]
    #pragma unroll
    for (int r = 0; r < 8; ++r) {
        float v = zpv[r];
        v += __shfl_xor(v, 1, 64);
        v += __shfl_xor(v, 2, 64);
        v += __shfl_xor(v, 4, 64);
        v += __shfl_xor(v, 8, 64);
        v += __shfl_xor(v, 16, 64);
        v += __shfl_xor(v, 32, 64);
        zpv[r] = v;
    }
    if (lane == 0) {
        #pragma unroll
        for (int r = 0; r < 8; ++r)
            Zpart[((h << 9) + i0 + r) * 8 + w] = zpv[r];
    }
}

// ---------------- ctx (r8/r16, unchanged): sum_j max(v,z') - Zsum ----------------
__global__ __launch_bounds__(512) void ctx_kernel(
    const float* __restrict__ V, const float* __restrict__ zp,
    const float* __restrict__ Zpart, __bf16* __restrict__ ctxb)
{
    int blk = blockIdx.x;
    int h = blk >> 6;
    int it = blk & 63;
    int i0 = it << 3;
    int c0 = h << 6;
    int u = threadIdx.x;
    int w = u >> 6, lane = u & 63;

    __shared__ float part[8][8][64];

    int wu = __builtin_amdgcn_readfirstlane(w);
    float acc[8][4] = {};

    #pragma unroll
    for (int cch = 0; cch < 4; ++cch) {
        int jg = (cch << 7) + (wu << 4);
        float vv[16];
        #pragma unroll
        for (int t = 0; t < 16; ++t)
            vv[t] = V[(jg + t) * Dm + c0 + lane];

        const float* zbase = zp + ((h << 9) + i0) * S + jg;
        #pragma unroll
        for (int ii = 0; ii < 8; ++ii) {
            const float* zrow = zbase + ii * S;
            #pragma unroll
            for (int q4 = 0; q4 < 4; ++q4) {
                float4 z4 = *(const float4*)(zrow + (q4 << 2));
                acc[ii][0] += fmaxf(vv[(q4 << 2) + 0], z4.x);
                acc[ii][1] += fmaxf(vv[(q4 << 2) + 1], z4.y);
                acc[ii][2] += fmaxf(vv[(q4 << 2) + 2], z4.z);
                acc[ii][3] += fmaxf(vv[(q4 << 2) + 3], z4.w);
            }
        }
    }

    #pragma unroll
    for (int ii = 0; ii < 8; ++ii)
        part[w][ii][lane] = (acc[ii][0] + acc[ii][1]) + (acc[ii][2] + acc[ii][3]);
    __syncthreads();
    {
        int ii = u >> 6;
        float s = 0.f;
        #pragma unroll
        for (int ww = 0; ww < 8; ++ww) s += part[ww][ii][lane];
        float zsum = 0.f;
        const float* zpr = Zpart + ((h << 9) + (i0 + ii)) * 8;
        #pragma unroll
        for (int p = 0; p < 8; ++p) zsum += zpr[p];
        ctxb[(i0 + ii) * Dm + c0 + lane] = (__bf16)(s - zsum);
    }
}

extern "C" void kernel_launch(void* const* d_in, const int* in_sizes, int n_in,
                              void* d_out, int out_size, void* d_ws, size_t ws_size,
                              hipStream_t stream) {
    const float* hs    = (const float*)d_in[0];
    const float* mask  = (const float*)d_in[1];
    const float* Wq    = (const float*)d_in[2];
    const float* bq    = (const float*)d_in[3];
    const float* Wk    = (const float*)d_in[4];
    const float* bk    = (const float*)d_in[5];
    const float* Wv    = (const float*)d_in[6];
    const float* bv    = (const float*)d_in[7];
    const float* Wo    = (const float*)d_in[8];
    const float* bo    = (const float*)d_in[9];
    const float* gamma = (const float*)d_in[10];
    const float* alpha = (const float*)d_in[11];
    float* out = (float*)d_out;

    char* base = (char*)d_ws;
    float*  zp    = (float*)(base);                               // 8 MB
    float*  Zpart = (float*)(base + (8u << 20));                  // 128 KB
    float*  QT    = (float*)(base + (8u << 20) + (128u << 10));   // 1 MB (transposed)
    float*  KT    = QT + S * Dm;                                  // 1 MB (transposed)
    float*  Vb    = KT + S * Dm;                                  // 1 MB (normal)
    __bf16* Cbf   = (__bf16*)(Vb + S * Dm);                       // 0.5 MB

    hipLaunchKernelGGL((gemm_icvt<false, true>), dim3(768), dim3(256), 0, stream,
                       (const void*)hs, Wq, Wk, Wv, bq, bk, bv, QT, KT, Vb);
    hipLaunchKernelGGL(zT_kernel, dim3(512), dim3(512), 0, stream,
                       QT, KT, mask, gamma, alpha, zp, Zpart);
    hipLaunchKernelGGL(ctx_kernel, dim3(512), dim3(512), 0, stream,
                       Vb, zp, Zpart, Cbf);
    hipLaunchKernelGGL((gemm_icvt<true, false>), dim3(256), dim3(256), 0, stream,
                       (const void*)Cbf, Wo, Wo, Wo, bo, bo, bo, out, out, out);
}